// Round 9
// baseline (164.499 us; speedup 1.0000x reference)
//
#include <hip/hip_runtime.h>
#include <hip/hip_bf16.h>
#include <hip/hip_fp16.h>
#include <math.h>

// ---------------- problem constants ----------------
#define ROWS  16384           // B*S
#define DM    1024
#define DS    64
#define NUSE  928             // 512+256+128+32
#define NPAD  960             // padded to 15 tiles of 64
#define RPB   16              // rows per block
#define NBLK  (ROWS/RPB)      // 1024

typedef __attribute__((ext_vector_type(8))) short bf16x8;
typedef __attribute__((ext_vector_type(4))) float f32x4;

static __device__ inline f32x4 mfma16(bf16x8 a, bf16x8 b, f32x4 c) {
    return __builtin_amdgcn_mfma_f32_16x16x32_bf16(a, b, c, 0, 0, 0);
}

// split fp32 -> bf16 hi + bf16 lo (RNE both), v ~= hi + lo to ~2^-18 rel
static __device__ inline void bfsplit(float v, unsigned short& h, unsigned short& l) {
    unsigned u = __float_as_uint(v);
    unsigned hr = u + 0x7FFFu + ((u >> 16) & 1u);
    h = (unsigned short)(hr >> 16);
    float hf = __uint_as_float((unsigned)h << 16);
    float r = v - hf;
    unsigned ur = __float_as_uint(r);
    unsigned lr2 = ur + 0x7FFFu + ((ur >> 16) & 1u);
    l = (unsigned short)(lr2 >> 16);
}

// ---------------- workspace byte offsets ----------------
#define OFF_EBH  0LL
#define OFF_EBL  122880LL
#define OFF_WBH  245760LL
#define OFF_WBL  376832LL
#define OFF_WP   507904LL                  // wpart fp32 [1024][960] = 3.93 MB
#define OFF_WR   4440064LL                 // wred fp32 [8][960]

// ---------------- k_prep: emb normalize+split AND W split (merged) ----------------
__global__ __launch_bounds__(256) void k_prep(const float* __restrict__ emb,
                                              const float* __restrict__ W,
                                              unsigned short* __restrict__ ebh,
                                              unsigned short* __restrict__ ebl,
                                              unsigned short* __restrict__ wbh,
                                              unsigned short* __restrict__ wbl) {
    if (blockIdx.x < 4) {
        int n = blockIdx.x * 256 + threadIdx.x;
        if (n >= NPAD) return;
        if (n >= NUSE) {
            #pragma unroll
            for (int d = 0; d < DS; d++) {
                int kt = d >> 5, q = (d >> 3) & 3, j = d & 7;
                int a = ((kt * 4 + q) * NPAD + n) * 8 + j;
                ebh[a] = 0; ebl[a] = 0;
            }
            return;
        }
        float ss = 0.f;
        #pragma unroll
        for (int d = 0; d < DS; d++) { float v = emb[n * DS + d]; ss = fmaf(v, v, ss); }
        float inv = 1.0f / sqrtf(ss);
        #pragma unroll
        for (int d = 0; d < DS; d++) {
            float v = emb[n * DS + d] * inv;
            unsigned short h, l; bfsplit(v, h, l);
            int kt = d >> 5, q = (d >> 3) & 3, j = d & 7;
            int a = ((kt * 4 + q) * NPAD + n) * 8 + j;
            ebh[a] = h; ebl[a] = l;
        }
    } else {
        int idx = (blockIdx.x - 4) * 256 + threadIdx.x;   // 0..2047
        int ktg = idx >> 6, n = idx & 63;
        #pragma unroll
        for (int q = 0; q < 4; q++) {
            #pragma unroll
            for (int j = 0; j < 8; j++) {
                int k = ktg * 32 + q * 8 + j;
                float v = W[k * DS + n];
                unsigned short h, l; bfsplit(v, h, l);
                int a = ((ktg * 4 + q) * 64 + n) * 8 + j;
                wbh[a] = h; wbl[a] = l;
            }
        }
    }
}

// ---------------- k_mega ----------------
// 1024 blocks x 512 thr (8 waves), 16 rows/block, LDS 40960 B -> 4 blocks/CU,
// 32 waves/CU. Phase A: 8-way K-split(128), x read DIRECT from global in A-frag
// order (16x128B contiguous rows, no staging LDS, no K-loop barriers).
// H-build: 512-thread cooperative reduce of 8 K-partials + bias -> bf16 frags.
// Phase 1: 8 waves x 2 n-tiles: logits MFMA + exp -> Ph (fp16 LDS) + Z partials.
// Phase 2: weighted column reduce -> wpart.
__global__ __launch_bounds__(512, 4) void k_mega(const float* __restrict__ x,
                                                 const float* __restrict__ bias,
                                                 const unsigned short* __restrict__ wbh,
                                                 const unsigned short* __restrict__ wbl,
                                                 const unsigned short* __restrict__ ebh,
                                                 const unsigned short* __restrict__ ebl,
                                                 const float* __restrict__ imp,
                                                 float* __restrict__ wpart) {
    __shared__ __align__(16) unsigned char smem[40960];
    // region0 [0,34560): Cb fp32 [w8][16*66] (phase A) THEN Ph fp16 [n960][18] (phase 1/2)
    unsigned short* Ph    = (unsigned short*)smem;
    float*          Cb    = (float*)smem;
    unsigned short* Hh    = (unsigned short*)(smem + 34560);  // [kt2][q4][r16][j8]
    unsigned short* Hl    = (unsigned short*)(smem + 36608);
    float*          zslot = (float*)(smem + 38656);           // [w8][sl4][r16]
    float*          coefL = (float*)(smem + 40704);           // [r16][sl4]

    const int tid = threadIdx.x;
    const int rc = blockIdx.x;
    const long long row0 = (long long)rc * RPB;
    const int w = tid >> 6, lane = tid & 63, q = lane >> 4, lm = lane & 15;

    zslot[tid] = 0.f;   // 512 floats exactly

    // ======== phase A: h K-partials, direct-global A-frags, no barriers ========
    {
        const int kg = w;   // this wave owns K [kg*128, kg*128+128)
        const float* xp = &x[(row0 + lm) * (long long)DM + kg * 128 + q * 8];
        f32x4 acc[4];
        #pragma unroll
        for (int f = 0; f < 4; f++) { acc[f].x = 0.f; acc[f].y = 0.f; acc[f].z = 0.f; acc[f].w = 0.f; }

        #pragma unroll
        for (int ks = 0; ks < 4; ks++) {
            float4 v0 = *(const float4*)&xp[ks * 32];
            float4 v1 = *(const float4*)&xp[ks * 32 + 4];
            union { bf16x8 v; unsigned short s[8]; } ah, al;
            bfsplit(v0.x, ah.s[0], al.s[0]); bfsplit(v0.y, ah.s[1], al.s[1]);
            bfsplit(v0.z, ah.s[2], al.s[2]); bfsplit(v0.w, ah.s[3], al.s[3]);
            bfsplit(v1.x, ah.s[4], al.s[4]); bfsplit(v1.y, ah.s[5], al.s[5]);
            bfsplit(v1.z, ah.s[6], al.s[6]); bfsplit(v1.w, ah.s[7], al.s[7]);
            const int ktg = kg * 4 + ks;
            #pragma unroll
            for (int f = 0; f < 4; f++) {
                const int ba = ((ktg * 4 + q) * 64 + f * 16 + lm) * 8;
                const bf16x8 b_h = *(const bf16x8*)&wbh[ba];
                const bf16x8 b_l = *(const bf16x8*)&wbl[ba];
                acc[f] = mfma16(ah.v, b_h, acc[f]);
                acc[f] = mfma16(ah.v, b_l, acc[f]);
                acc[f] = mfma16(al.v, b_h, acc[f]);
            }
        }
        // write K-partial tile to Cb: [w][row16][col64], row stride 66 (2-way banks)
        #pragma unroll
        for (int f = 0; f < 4; f++)
            #pragma unroll
            for (int t = 0; t < 4; t++)
                Cb[w * 1056 + (q * 4 + t) * 66 + f * 16 + lm] = acc[f][t];
    }
    __syncthreads();

    // ======== H-build: reduce 8 K-partials + bias -> split A-frags ========
    #pragma unroll
    for (int ee = 0; ee < 2; ee++) {
        const int e = tid + ee * 512;          // 0..1023
        const int row = e >> 6, col = e & 63;
        float s = bias[col];
        #pragma unroll
        for (int g = 0; g < 8; g++) s += Cb[g * 1056 + row * 66 + col];
        unsigned short hh, ll; bfsplit(s, hh, ll);
        const int kt = col >> 5, qH = (col >> 3) & 3, jH = col & 7;
        const int hidx = ((kt * 4 + qH) * RPB + row) * 8 + jH;
        Hh[hidx] = hh; Hl[hidx] = ll;
    }
    __syncthreads();   // H visible; Cb reads done -> Ph (alias) writable

    // ======== phase 1: logits + exp -> Ph, Z partials ========
    bf16x8 a_h[2], a_l[2];
    #pragma unroll
    for (int kt = 0; kt < 2; kt++) {
        const int ab = ((kt * 4 + q) * RPB + lm) * 8;
        a_h[kt] = *(const bf16x8*)&Hh[ab];
        a_l[kt] = *(const bf16x8*)&Hl[ab];
    }

    #pragma unroll
    for (int v = 0; v < 2; v++) {
        const int nt = w + v * 8;
        if (nt > 14) continue;
        f32x4 acc2[4];
        #pragma unroll
        for (int f = 0; f < 4; f++) { acc2[f].x = 0.f; acc2[f].y = 0.f; acc2[f].z = 0.f; acc2[f].w = 0.f; }
        #pragma unroll
        for (int kt = 0; kt < 2; kt++) {
            #pragma unroll
            for (int f = 0; f < 4; f++) {
                const int bb = ((kt * 4 + q) * NPAD + nt * 64 + f * 16 + lm) * 8;
                const bf16x8 b_h = *(const bf16x8*)&ebh[bb];
                const bf16x8 b_l = *(const bf16x8*)&ebl[bb];
                acc2[f] = mfma16(a_h[kt], b_h, acc2[f]);
                acc2[f] = mfma16(a_h[kt], b_l, acc2[f]);
                acc2[f] = mfma16(a_l[kt], b_h, acc2[f]);
            }
        }
        const int sl = (nt < 8) ? 0 : (nt < 12) ? 1 : (nt < 14) ? 2 : 3;
        float s0 = 0.f, s1 = 0.f, s2 = 0.f, s3 = 0.f;
        #pragma unroll
        for (int f = 0; f < 4; f++) {
            float e0 = __expf(acc2[f][0]);
            float e1 = __expf(acc2[f][1]);
            float e2 = __expf(acc2[f][2]);
            float e3 = __expf(acc2[f][3]);
            const int n = nt * 64 + f * 16 + lm;
            unsigned short p0 = __half_as_ushort(__float2half(e0));
            unsigned short p1 = __half_as_ushort(__float2half(e1));
            unsigned short p2 = __half_as_ushort(__float2half(e2));
            unsigned short p3 = __half_as_ushort(__float2half(e3));
            // Ph[n][row]: rows q*4..q*4+3, dword stores only (36 B n-stride)
            *(unsigned*)&Ph[n * 18 + q * 4]     = (unsigned)p0 | ((unsigned)p1 << 16);
            *(unsigned*)&Ph[n * 18 + q * 4 + 2] = (unsigned)p2 | ((unsigned)p3 << 16);
            if (nt * 64 + f * 16 < NUSE) {   // exclude pad cols (nt14 f2,f3)
                s0 += e0; s1 += e1; s2 += e2; s3 += e3;
            }
        }
        #pragma unroll
        for (int off = 1; off < 16; off <<= 1) {
            s0 += __shfl_xor(s0, off); s1 += __shfl_xor(s1, off);
            s2 += __shfl_xor(s2, off); s3 += __shfl_xor(s3, off);
        }
        if (lm < 4) {
            float sv = (lm == 0) ? s0 : (lm == 1) ? s1 : (lm == 2) ? s2 : s3;
            zslot[(w * 4 + sl) * RPB + q * 4 + lm] += sv;   // per-wave slot: no race
        }
    }
    __syncthreads();

    // ---- Z + coef ----
    if (tid < RPB) {
        const int r = tid;
        const float im = imp[row0 + r];
        #pragma unroll
        for (int sl = 0; sl < 4; sl++) {
            float Z = 0.f;
            #pragma unroll
            for (int g = 0; g < 8; g++) Z += zslot[(g * 4 + sl) * RPB + r];
            coefL[r * 4 + sl] = im / Z;
        }
    }
    __syncthreads();

    // ======== phase 2: weighted column reduce ========
    for (int nn = tid; nn < NUSE; nn += 512) {
        const int sl = (nn < 512) ? 0 : (nn < 768) ? 1 : (nn < 896) ? 2 : 3;
        float accw = 0.f;
        #pragma unroll
        for (int rb = 0; rb < 8; rb++) {
            const unsigned pk = *(const unsigned*)&Ph[nn * 18 + rb * 2];
            float v0 = __half2float(__ushort_as_half((unsigned short)(pk & 0xFFFF)));
            float v1 = __half2float(__ushort_as_half((unsigned short)(pk >> 16)));
            accw = fmaf(coefL[(rb * 2 + 0) * 4 + sl], v0, accw);
            accw = fmaf(coefL[(rb * 2 + 1) * 4 + sl], v1, accw);
        }
        wpart[(long long)rc * NPAD + nn] = accw;
    }
}

// ---------------- k_red: parallel chunk-reduction wpart[1024][960] -> wred[8][960] ----------------
__global__ __launch_bounds__(256) void k_red(const float* __restrict__ wpart,
                                             float* __restrict__ wred) {
    const int g = blockIdx.x;       // 0..28
    const int b = blockIdx.y;       // 0..7
    const int tid = threadIdx.x;
    const int n = g * 32 + (tid & 31);
    const int cp = tid >> 5;        // 0..7
    float s = 0.f;
    #pragma unroll 2
    for (int c = cp; c < 128; c += 8)
        s += wpart[(long long)(b * 128 + c) * NPAD + n];
    __shared__ float red[8][32];
    red[cp][tid & 31] = s;
    __syncthreads();
    if (tid < 32) {
        float t = 0.f;
        #pragma unroll
        for (int p = 0; p < 8; p++) t += red[p][tid];
        wred[b * 960 + g * 32 + tid] = t;
    }
}

// ---------------- k_rank: ranks + outputs from wred ----------------
__global__ __launch_bounds__(512) void k_rank(const float* __restrict__ wred,
                                              float* __restrict__ out) {
    const int b = blockIdx.x;
    const int tid = threadIdx.x;
    __shared__ float w_s[NUSE];
    __shared__ int   rk[NUSE];

    for (int n = tid; n < NUSE; n += 512) {
        float s = wred[b * 960 + n];
        w_s[n] = s;
        if (n < 512)      out[3072 + (long long)b * 512 + n] = s;
        else if (n < 768) out[7168 + (long long)b * 256 + (n - 512)] = s;
    }
    __syncthreads();

    for (int n = tid; n < NUSE; n += 512) {
        int lo, hi;
        if (n < 512)      { lo = 0;   hi = 512; }
        else if (n < 768) { lo = 512; hi = 768; }
        else if (n < 896) { lo = 768; hi = 896; }
        else              { lo = 896; hi = NUSE; }
        float wn = w_s[n];
        int r = 0;
        for (int m = lo; m < hi; m++) {
            float wm = w_s[m];
            r += (wm > wn) || ((wm == wn) && (m < n));
        }
        rk[n] = r;
    }
    __syncthreads();

    if (tid < 512) {
        int n = tid;
        if (rk[n] < 64) {
            int pos = 0;
            for (int m = 0; m < n; m++) pos += (rk[m] < 64) ? 1 : 0;
            out[(long long)b * 64 + pos] = (float)n;
        }
    }
    if (tid < 256) {
        int n = 512 + tid;
        if (rk[n] < 32) {
            int pos = 0;
            for (int m = 512; m < n; m++) pos += (rk[m] < 32) ? 1 : 0;
            out[512 + (long long)b * 32 + pos] = (float)tid;
        }
    }
    if (tid < 128) {
        int n = 768 + tid;
        float v = (rk[n] < 16) ? w_s[n] : 0.f;
        out[768 + (long long)b * 128 + tid] = v;
        out[1792 + (long long)b * 128 + tid] = v;
    }
    if (tid < 32) {
        int n = 896 + tid;
        float v = (rk[n] < 3) ? w_s[n] : 0.f;
        out[2816 + (long long)b * 32 + tid] = v;
    }
}

// ---------------- launch ----------------
extern "C" void kernel_launch(void* const* d_in, const int* in_sizes, int n_in,
                              void* d_out, int out_size, void* d_ws, size_t ws_size,
                              hipStream_t stream) {
    const float* x    = (const float*)d_in[0];
    const float* imp  = (const float*)d_in[1];
    const float* W    = (const float*)d_in[2];
    const float* bias = (const float*)d_in[3];
    const float* emb  = (const float*)d_in[4];

    char* ws = (char*)d_ws;
    unsigned short* ebh = (unsigned short*)(ws + OFF_EBH);
    unsigned short* ebl = (unsigned short*)(ws + OFF_EBL);
    unsigned short* wbh = (unsigned short*)(ws + OFF_WBH);
    unsigned short* wbl = (unsigned short*)(ws + OFF_WBL);
    float* wpart        = (float*)(ws + OFF_WP);
    float* wred         = (float*)(ws + OFF_WR);
    float* out          = (float*)d_out;

    k_prep<<<12, 256, 0, stream>>>(emb, W, ebh, ebl, wbh, wbl);
    k_mega<<<NBLK, 512, 0, stream>>>(x, bias, wbh, wbl, ebh, ebl, imp, wpart);
    k_red<<<dim3(29, 8), 256, 0, stream>>>(wpart, wred);
    k_rank<<<8, 512, 0, stream>>>(wred, out);
}